// Round 2
// baseline (606.557 us; speedup 1.0000x reference)
//
#include <hip/hip_runtime.h>

typedef __bf16 bf16_t;
typedef __attribute__((ext_vector_type(8))) __bf16 bf16x8;
typedef __attribute__((ext_vector_type(4))) float f32x4;

#define M_DIM 8192   // BSZ*SEQ
#define N_DIM 4096   // OUT_DIM
#define K_DIM 4096   // IN_DIM
#define R_DIM 64     // total rank

// ---------------- kernel 1: x fp32 -> bf16 ----------------
__global__ __launch_bounds__(256) void cvt_x(const float* __restrict__ in,
                                             bf16_t* __restrict__ out) {
    size_t i = ((size_t)blockIdx.x * 256 + threadIdx.x) * 8;
    float4 a = *(const float4*)(in + i);
    float4 b = *(const float4*)(in + i + 4);
    bf16x8 v;
    v[0] = (bf16_t)a.x; v[1] = (bf16_t)a.y; v[2] = (bf16_t)a.z; v[3] = (bf16_t)a.w;
    v[4] = (bf16_t)b.x; v[5] = (bf16_t)b.y; v[6] = (bf16_t)b.z; v[7] = (bf16_t)b.w;
    *(bf16x8*)(out + i) = v;
}

// ------- kernel 2: Weff[o][i] = bf16(W[o][i] + sum_r (2*B[o][r])*A[r][i]) -------
// Bl block (16 rows x 64 ranks, 4 KiB) staged to LDS once; inner loop reads it
// with ds_read_b128 at a lane-uniform address (broadcast, conflict-free).
// This removes any dependence on hipcc scalarizing the uniform Bl loads (the
// suspected ~250us pathology: per-lane vector loads / s_load storms).
__global__ __launch_bounds__(256) void build_weff(const float* __restrict__ W,
                                                  const float* __restrict__ A,
                                                  const float* __restrict__ Bl,
                                                  bf16_t* __restrict__ out) {
    __shared__ __attribute__((aligned(16))) float bls[16 * R_DIM];  // 4 KiB

    const int i  = blockIdx.x * 256 + threadIdx.x;
    const int o0 = blockIdx.y * 16;

    {   // cooperative stage: 1024 floats / 256 threads = 4 each
        const int t = threadIdx.x;
        float4 v = *(const float4*)(Bl + o0 * R_DIM + t * 4);
        *(float4*)(bls + t * 4) = v;
    }
    __syncthreads();

    float acc[16];
#pragma unroll
    for (int j = 0; j < 16; j++) acc[j] = W[(size_t)(o0 + j) * K_DIM + i];

    for (int rh = 0; rh < R_DIM; rh += 16) {   // NOT unrolled: keeps pressure low
        float av[16];
#pragma unroll
        for (int r = 0; r < 16; r++) av[r] = 2.0f * A[(size_t)(rh + r) * K_DIM + i];
#pragma unroll
        for (int j = 0; j < 16; j++) {
#pragma unroll
            for (int rq = 0; rq < 4; rq++) {
                float4 b = *(const float4*)(bls + j * R_DIM + rh + rq * 4);
                acc[j] = fmaf(b.x, av[rq * 4 + 0], acc[j]);
                acc[j] = fmaf(b.y, av[rq * 4 + 1], acc[j]);
                acc[j] = fmaf(b.z, av[rq * 4 + 2], acc[j]);
                acc[j] = fmaf(b.w, av[rq * 4 + 3], acc[j]);
            }
        }
    }
#pragma unroll
    for (int j = 0; j < 16; j++) out[(size_t)(o0 + j) * K_DIM + i] = (bf16_t)acc[j];
}

// ---------------- kernel 3: C[M][N] = Xb[M][K] * Weff[N][K]^T ----------------
// 256x256 tile, BK=64, 8 waves (2x4), 4 phases/K-tile, raw s_barrier + counted
// s_waitcnt vmcnt(4).
//
// ROUND-2 CHANGE: every LDS staging buffer is its own __shared__ OBJECT and all
// buffer selection is STATIC (explicit even/odd K-tile bodies). Round-1 used
// Ash[cur] with runtime cur: LLVM's LDS-DMA alias tracking could not prove the
// in-flight global_load_lds writes don't alias the ds_read sources and inserted
// its own s_waitcnt vmcnt(0) per phase -> measured exactly the drain-0 plateau
// (305us, MfmaUtil 39%). Distinct objects give NoAlias regardless of offsets,
// leaving only the explicit counted waits.
//
// vmcnt ledger (per-wave, 2 loads per stage unit), tile t phases P1..P4:
//   stages: P1 A-k0(t+1), P2 B-k0(t+1), P3 A-k1(t+1), P4 B-k1(t+1)
//   P2-end WAITV(4): newest 4 = {A-k0,B-k0}(t+1) => {A-k1,B-k1}(t) resident
//   P4-end WAITV(4): newest 4 = {A-k1,B-k1}(t+1) => {A-k0,B-k0}(t+1) resident
//   Last tile: no prefetch, P2 drains with WAITV(0), P4 no wait.
#define BM 256
#define BN 256
#define BK 64
#define NT (K_DIM / BK)

#define GLDS(gp, lp) __builtin_amdgcn_global_load_lds(                       \
    (__attribute__((address_space(1))) void*)(gp),                           \
    (__attribute__((address_space(3))) void*)(lp), 16, 0, 0)

#define SBAR() __builtin_amdgcn_s_barrier()
#define WAITV(n) asm volatile("s_waitcnt vmcnt(" #n ")" ::: "memory")

// read 4 A fragments (rows mbase..mbase+3 of the wave's 8) from a [256][32] half
#define READ_A(ARR, mbase)                                                   \
    _Pragma("unroll")                                                        \
    for (int mf = 0; mf < 4; ++mf)                                           \
        afr[mf] = *(const bf16x8*)(&ARR[0][0] + aoff[(mbase) + mf]);

#define READ_B(ARR)                                                          \
    _Pragma("unroll")                                                        \
    for (int nf = 0; nf < 4; ++nf)                                           \
        bfr[nf] = *(const bf16x8*)(&ARR[0][0] + boff[nf]);

#define MFMA_HALF(mbase)                                                     \
    __builtin_amdgcn_s_setprio(1);                                           \
    _Pragma("unroll")                                                        \
    for (int mf = 0; mf < 4; ++mf)                                           \
        _Pragma("unroll")                                                    \
        for (int nf = 0; nf < 4; ++nf)                                       \
            acc[(mbase) + mf][nf] = __builtin_amdgcn_mfma_f32_16x16x32_bf16( \
                afr[mf], bfr[nf], acc[(mbase) + mf][nf], 0, 0, 0);           \
    __builtin_amdgcn_s_setprio(0);

// stage one k-half unit (256 rows x 32 k): 2 x global_load_lds(16B)/thread.
// LDS dest linear (wave-uniform base + lane*16); source 16B chunk pre-swizzled
// so LDS[row][c] = global chunk c ^ ((row>>1)&3).
#define STAGE(SRC, ROW0, KB, DST)                                            \
    _Pragma("unroll")                                                        \
    for (int j_ = 0; j_ < 2; ++j_) {                                         \
        const int g_  = wave * 2 + j_;                                       \
        const int r_  = g_ * 16 + srow;                                      \
        const int cs_ = sc ^ ((r_ >> 1) & 3);                                \
        GLDS(SRC + (size_t)((ROW0) + r_) * K_DIM + (KB) + cs_ * 8,           \
             &DST[0][0] + g_ * 512);                                         \
    }

// one K-tile: read {RA0,RA1,RB0,RB1} (k-halves), stage tile kn/BK into
// {SA0,SA1,SB0,SB1}. pf=false only on the final tile.
#define KBODY(RA0, RA1, RB0, RB1, SA0, SA1, SB0, SB1, kn, pf)                \
    {                                                                        \
        bf16x8 afr[4], bfr[4];                                               \
        /* P1: mf0-3 x k0 ; prefetch A-k0(next) */                           \
        READ_B(RB0); READ_A(RA0, 0);                                         \
        if (pf) { STAGE(Ax, m0, kn, SA0); }                                  \
        SBAR(); MFMA_HALF(0); SBAR();                                        \
        /* P2: mf4-7 x k0 ; prefetch B-k0(next) ; ensure k1(cur) resident */ \
        READ_A(RA0, 4);                                                      \
        if (pf) { STAGE(Bw, n0, kn, SB0); }                                  \
        SBAR(); MFMA_HALF(4);                                                \
        if (pf) { WAITV(4); } else { WAITV(0); }                             \
        SBAR();                                                              \
        /* P3: mf0-3 x k1 ; prefetch A-k1(next) */                           \
        READ_B(RB1); READ_A(RA1, 0);                                         \
        if (pf) { STAGE(Ax, m0, (kn) + 32, SA1); }                           \
        SBAR(); MFMA_HALF(0); SBAR();                                        \
        /* P4: mf4-7 x k1 ; prefetch B-k1(next) ; ensure k0(next) resident */\
        READ_A(RA1, 4);                                                      \
        if (pf) { STAGE(Bw, n0, (kn) + 32, SB1); }                           \
        SBAR(); MFMA_HALF(4);                                                \
        if (pf) { WAITV(4); }                                                \
        SBAR();                                                              \
    }

__global__ __launch_bounds__(512, 2) void gemm_bf16(const bf16_t* __restrict__ Ax,
                                                    const bf16_t* __restrict__ Bw,
                                                    float* __restrict__ C) {
    // 8 distinct LDS objects: {A,B} x {buf0,buf1} x {khalf0,khalf1}, 16 KiB each
    __shared__ __attribute__((aligned(16))) bf16_t As0a[256][32], As0b[256][32];
    __shared__ __attribute__((aligned(16))) bf16_t As1a[256][32], As1b[256][32];
    __shared__ __attribute__((aligned(16))) bf16_t Bs0a[256][32], Bs0b[256][32];
    __shared__ __attribute__((aligned(16))) bf16_t Bs1a[256][32], Bs1b[256][32];

    const int tid  = threadIdx.x;
    const int wave = (tid >> 6) & 7;
    const int lane = tid & 63;
    const int m16  = lane & 15;
    const int quad = lane >> 4;
    const int wm   = wave >> 2;   // 0..1 -> 128-row half
    const int wn   = wave & 3;    // 0..3 -> 64-col quarter

    // XCD-aware bijective swizzle (512 blocks, 512 % 8 == 0)
    const int fid = blockIdx.y * 16 + blockIdx.x;
    const int swz = (fid & 7) * 64 + (fid >> 3);
    const int m0  = (swz >> 4) * BM;
    const int n0  = (swz & 15) * BN;

    // staging lane geometry: row = group*16 + (lane>>2), chunk = lane&3
    const int srow = lane >> 2;
    const int sc   = lane & 3;

    // consumption offsets (elements) into a [256][32] k-half
    int aoff[8], boff[4];
#pragma unroll
    for (int mf = 0; mf < 8; ++mf) {
        const int mr = wm * 128 + mf * 16 + m16;
        aoff[mf] = mr * 32 + ((quad ^ ((mr >> 1) & 3)) << 3);
    }
#pragma unroll
    for (int nf = 0; nf < 4; ++nf) {
        const int nr = wn * 64 + nf * 16 + m16;
        boff[nf] = nr * 32 + ((quad ^ ((nr >> 1) & 3)) << 3);
    }

    f32x4 acc[8][4] = {};

    // prologue: stage tile 0 into buf0 objects
    STAGE(Ax, m0, 0,  As0a);
    STAGE(Bw, n0, 0,  Bs0a);
    STAGE(Ax, m0, 32, As0b);
    STAGE(Bw, n0, 32, Bs0b);
    WAITV(4);          // k0 pair resident; k1 pair covered by tile0-P2's wait
    SBAR();

#pragma unroll 1
    for (int t = 0; t < NT; t += 2) {
        // even tile t: read buf0, stage tile t+1 -> buf1 (t+1 < NT always here)
        KBODY(As0a, As0b, Bs0a, Bs0b, As1a, As1b, Bs1a, Bs1b,
              (t + 1) * BK, true);
        // odd tile t+1: read buf1, stage tile t+2 -> buf0
        const bool pf2 = (t + 2) < NT;
        KBODY(As1a, As1b, Bs1a, Bs1b, As0a, As0b, Bs0a, Bs0b,
              (t + 2) * BK, pf2);
    }

    // epilogue: C/D layout col = lane&15, row = quad*4 + reg
#pragma unroll
    for (int mf = 0; mf < 8; ++mf) {
#pragma unroll
        for (int i = 0; i < 4; ++i) {
            const int gm = m0 + wm * 128 + mf * 16 + quad * 4 + i;
            float* crow = C + (size_t)gm * N_DIM + n0 + wn * 64 + m16;
#pragma unroll
            for (int nf = 0; nf < 4; ++nf)
                crow[nf * 16] = acc[mf][nf][i];
        }
    }
}

extern "C" void kernel_launch(void* const* d_in, const int* in_sizes, int n_in,
                              void* d_out, int out_size, void* d_ws, size_t ws_size,
                              hipStream_t stream) {
    const float* x  = (const float*)d_in[0];
    const float* W  = (const float*)d_in[1];
    const float* La = (const float*)d_in[2];
    const float* Lb = (const float*)d_in[3];
    float* out = (float*)d_out;

    // workspace: xb (64 MiB) | Weff (32 MiB)
    bf16_t* xb = (bf16_t*)d_ws;
    bf16_t* wf = (bf16_t*)((char*)d_ws + (size_t)M_DIM * K_DIM * sizeof(bf16_t));

    cvt_x<<<(M_DIM * K_DIM) / (256 * 8), 256, 0, stream>>>(x, xb);
    build_weff<<<dim3(K_DIM / 256, N_DIM / 16), 256, 0, stream>>>(W, La, Lb, wf);
    gemm_bf16<<<dim3(N_DIM / BN, M_DIM / BM), 512, 0, stream>>>(xb, wf, out);
}